// Round 8
// baseline (379.001 us; speedup 1.0000x reference)
//
#include <hip/hip_runtime.h>

#define BB 2
#define NN 2048
#define EE 768
#define HH 12
#define DD 64
#define MM (BB*NN)      // 4096
#define E3 (3*EE)       // 2304
#define NSPLIT 2
#define KEYS_PER_SPLIT (NN/NSPLIT)   // 1024 = 16 halves of 64
// 1/sqrt(768) * log2(e): scores in log2 domain -> P = exp2(s)
#define QSCALE 0.05205877280961602f

typedef __bf16 bf16x8 __attribute__((ext_vector_type(8)));
typedef float  f32x4  __attribute__((ext_vector_type(4)));
typedef unsigned short u16x8 __attribute__((ext_vector_type(8)));
typedef unsigned short u16x4 __attribute__((ext_vector_type(4)));

#define MFMA(a,b,c) __builtin_amdgcn_mfma_f32_16x16x32_bf16(a,b,c,0,0,0)

__device__ __forceinline__ unsigned short f2bf(float f) {
    unsigned int u = __float_as_uint(f);
    u += 0x7FFFu + ((u >> 16) & 1u);     // round-to-nearest-even
    return (unsigned short)(u >> 16);
}

__device__ __forceinline__ bf16x8 as_bf16x8(u16x8 v) {
    union { u16x8 u; bf16x8 b; } c; c.u = v; return c.b;
}

__device__ __forceinline__ bf16x8 combine48(u16x4 a, u16x4 b) {
    union { u16x4 q[2]; bf16x8 v; } c; c.q[0] = a; c.q[1] = b; return c.v;
}

typedef __attribute__((address_space(3))) unsigned int as3u32;
typedef __attribute__((address_space(1))) unsigned int as1u32;
__device__ __forceinline__ void gll16(const void* g, void* l) {
    // lane i deposits its 16B at lds_base + i*16 (wave-uniform dest base)
    __builtin_amdgcn_global_load_lds((const as1u32*)(uintptr_t)g,
                                     (as3u32*)(unsigned int)(uintptr_t)l, 16, 0, 0);
}

// ---------------------------------------------------------------------------
// fused f32 -> bf16 cast of x, w_qkv, w_o (contiguous dsts in ws)
// ---------------------------------------------------------------------------
#define XB4 786432   // (MM*EE)/4
#define WQ4 442368   // (E3*EE)/4
#define WO4 147456   // (EE*EE)/4
__global__ __launch_bounds__(256)
void cast3(const float* __restrict__ x, const float* __restrict__ wq,
           const float* __restrict__ wo, unsigned short* __restrict__ dst) {
    int i = blockIdx.x * 256 + threadIdx.x;
    const float* src;
    int off;
    if (i < XB4)            { src = x;  off = i; }
    else if (i < XB4+WQ4)   { src = wq; off = i - XB4; }
    else                    { src = wo; off = i - XB4 - WQ4; }
    float4 v = ((const float4*)src)[off];
    ushort4 o;
    o.x = f2bf(v.x); o.y = f2bf(v.y); o.z = f2bf(v.z); o.w = f2bf(v.w);
    ((ushort4*)dst)[i] = o;
}

// ---------------------------------------------------------------------------
// QKV GEMM v2: 128x64 tile, BK=32, 4 waves, double-buffered 2-phase pipeline.
// Grid (32,36) = 1152 blocks = 4.5 blocks/CU. LDS 24 KB.
// Scatter: q (scaled) [B][H][N][D], k [B][H][N][D], v transposed [B][H][D][N].
// ---------------------------------------------------------------------------
__global__ __launch_bounds__(256)
void gemm_qkv(const unsigned short* __restrict__ A, const unsigned short* __restrict__ W,
              const float* __restrict__ bias,
              unsigned short* __restrict__ o0, unsigned short* __restrict__ o1,
              unsigned short* __restrict__ o2)
{
    __shared__ unsigned short As[2][128 * 32];   // 16 KB
    __shared__ unsigned short Bs[2][64 * 32];    // 8 KB

    const int tid = threadIdx.x;
    const int l = tid & 63;
    const int w = tid >> 6;
    const int m0 = blockIdx.x * 128;
    const int c0 = blockIdx.y * 64;
    const int wm = (w >> 1) * 64;
    const int wn = (w & 1) * 32;

    // staging: 12 chunks of 16 rows x 32 k (8 A + 4 B); wave stages 3w..3w+2
    const unsigned short* s_src[3];
    int s_off[3]; bool s_isA[3];
    #pragma unroll
    for (int s = 0; s < 3; ++s) {
        const int ch = 3*w + s;
        if (ch < 8) {
            s_src[s] = A + (size_t)(m0 + ch*16 + (l>>2)) * EE + (l&3)*8;
            s_off[s] = ch*512; s_isA[s] = true;
        } else {
            s_src[s] = W + (size_t)(c0 + (ch-8)*16 + (l>>2)) * EE + (l&3)*8;
            s_off[s] = (ch-8)*512; s_isA[s] = false;
        }
    }

    const f32x4 zero4 = {0.f, 0.f, 0.f, 0.f};
    f32x4 acc[4][2];
    #pragma unroll
    for (int i = 0; i < 4; ++i)
        #pragma unroll
        for (int j = 0; j < 2; ++j) acc[i][j] = zero4;

    auto stage = [&](unsigned short* aB, unsigned short* bB, int k0) {
        #pragma unroll
        for (int s = 0; s < 3; ++s)
            gll16(s_src[s] + k0, (s_isA[s] ? aB : bB) + s_off[s]);
    };
    auto compute = [&](const unsigned short* aB, const unsigned short* bB) {
        bf16x8 af[4], bf[2];
        #pragma unroll
        for (int i = 0; i < 4; ++i)
            af[i] = *(const bf16x8*)&aB[(wm + 16*i + (l&15))*32 + (l>>4)*8];
        #pragma unroll
        for (int j = 0; j < 2; ++j)
            bf[j] = *(const bf16x8*)&bB[(wn + 16*j + (l&15))*32 + (l>>4)*8];
        #pragma unroll
        for (int i = 0; i < 4; ++i)
            #pragma unroll
            for (int j = 0; j < 2; ++j)
                acc[i][j] = MFMA(af[i], bf[j], acc[i][j]);
    };

    stage(As[0], Bs[0], 0);
    asm volatile("s_waitcnt vmcnt(0)" ::: "memory");
    __builtin_amdgcn_s_barrier();

    for (int k0 = 0; k0 < EE; k0 += 64) {
        stage(As[1], Bs[1], k0 + 32);          // k0+32 <= 736 < 768 always
        compute(As[0], Bs[0]);
        asm volatile("s_waitcnt vmcnt(0)" ::: "memory");
        __builtin_amdgcn_s_barrier();
        if (k0 + 64 < EE) stage(As[0], Bs[0], k0 + 64);
        compute(As[1], Bs[1]);
        asm volatile("s_waitcnt vmcnt(0)" ::: "memory");
        __builtin_amdgcn_s_barrier();
    }

    // epilogue: C/D col = l&15, row = (l>>4)*4 + r. Block = one (h,t) section.
    const int sec = c0 >> 6;               // = hh*3 + tt
    const int hh = sec / 3;
    const int tt = sec - hh*3;
    #pragma unroll
    for (int j = 0; j < 2; ++j) {
        const int col = c0 + wn + 16*j + (l&15);
        const int dcol = wn + 16*j + (l&15);   // 0..63 within section
        const float bj = bias[col];
        #pragma unroll
        for (int i = 0; i < 4; ++i) {
            const int row0 = m0 + wm + 16*i + (l>>4)*4;
            const int b = row0 >> 11;
            const int n = row0 & (NN - 1);
            if (tt == 2) {
                ushort4 pk;
                pk.x = f2bf(acc[i][j][0] + bj);
                pk.y = f2bf(acc[i][j][1] + bj);
                pk.z = f2bf(acc[i][j][2] + bj);
                pk.w = f2bf(acc[i][j][3] + bj);
                *(ushort4*)&o2[(((size_t)b*HH + hh)*DD + dcol)*NN + n] = pk;
            } else {
                unsigned short* dst = (tt == 0) ? o0 : o1;
                #pragma unroll
                for (int r = 0; r < 4; ++r) {
                    float val = acc[i][j][r] + bj;
                    if (tt == 0) val *= QSCALE;
                    dst[(((size_t)b*HH + hh)*NN + n + r)*DD + dcol] = f2bf(val);
                }
            }
        }
    }
}

// ---------------------------------------------------------------------------
// Output GEMM v2: 64x64 tile, BK=32, 4 waves, double-buffered 2-phase.
// Grid (64,12) = 768 blocks = 3 blocks/CU. LDS 16 KB.
// ---------------------------------------------------------------------------
__global__ __launch_bounds__(256)
void gemm_out(const unsigned short* __restrict__ A, const unsigned short* __restrict__ W,
              const float* __restrict__ bias, float* __restrict__ of)
{
    __shared__ unsigned short As[2][64 * 32];    // 8 KB
    __shared__ unsigned short Bs[2][64 * 32];    // 8 KB

    const int tid = threadIdx.x;
    const int l = tid & 63;
    const int w = tid >> 6;
    const int m0 = blockIdx.x * 64;
    const int c0 = blockIdx.y * 64;
    const int wm = (w >> 1) * 32;
    const int wn = (w & 1) * 32;

    // staging: 8 chunks of 16 rows x 32 k (4 A + 4 B); wave stages 2w, 2w+1
    const unsigned short* s_src[2];
    int s_off[2]; bool s_isA[2];
    #pragma unroll
    for (int s = 0; s < 2; ++s) {
        const int ch = 2*w + s;
        if (ch < 4) {
            s_src[s] = A + (size_t)(m0 + ch*16 + (l>>2)) * EE + (l&3)*8;
            s_off[s] = ch*512; s_isA[s] = true;
        } else {
            s_src[s] = W + (size_t)(c0 + (ch-4)*16 + (l>>2)) * EE + (l&3)*8;
            s_off[s] = (ch-4)*512; s_isA[s] = false;
        }
    }

    const f32x4 zero4 = {0.f, 0.f, 0.f, 0.f};
    f32x4 acc[2][2];
    #pragma unroll
    for (int i = 0; i < 2; ++i)
        #pragma unroll
        for (int j = 0; j < 2; ++j) acc[i][j] = zero4;

    auto stage = [&](unsigned short* aB, unsigned short* bB, int k0) {
        #pragma unroll
        for (int s = 0; s < 2; ++s)
            gll16(s_src[s] + k0, (s_isA[s] ? aB : bB) + s_off[s]);
    };
    auto compute = [&](const unsigned short* aB, const unsigned short* bB) {
        bf16x8 af[2], bf[2];
        #pragma unroll
        for (int i = 0; i < 2; ++i)
            af[i] = *(const bf16x8*)&aB[(wm + 16*i + (l&15))*32 + (l>>4)*8];
        #pragma unroll
        for (int j = 0; j < 2; ++j)
            bf[j] = *(const bf16x8*)&bB[(wn + 16*j + (l&15))*32 + (l>>4)*8];
        #pragma unroll
        for (int i = 0; i < 2; ++i)
            #pragma unroll
            for (int j = 0; j < 2; ++j)
                acc[i][j] = MFMA(af[i], bf[j], acc[i][j]);
    };

    stage(As[0], Bs[0], 0);
    asm volatile("s_waitcnt vmcnt(0)" ::: "memory");
    __builtin_amdgcn_s_barrier();

    for (int k0 = 0; k0 < EE; k0 += 64) {
        stage(As[1], Bs[1], k0 + 32);
        compute(As[0], Bs[0]);
        asm volatile("s_waitcnt vmcnt(0)" ::: "memory");
        __builtin_amdgcn_s_barrier();
        if (k0 + 64 < EE) stage(As[0], Bs[0], k0 + 64);
        compute(As[1], Bs[1]);
        asm volatile("s_waitcnt vmcnt(0)" ::: "memory");
        __builtin_amdgcn_s_barrier();
    }

    #pragma unroll
    for (int j = 0; j < 2; ++j) {
        const int col = c0 + wn + 16*j + (l&15);
        const float bj = bias[col];
        #pragma unroll
        for (int i = 0; i < 2; ++i) {
            #pragma unroll
            for (int r = 0; r < 4; ++r) {
                const int row = m0 + wm + 16*i + (l>>4)*4 + r;
                of[(size_t)row * EE + col] = acc[i][j][r] + bj;
            }
        }
    }
}

// ---------------------------------------------------------------------------
// MFMA flash attention, v8: NO LDS STAGING — direct L1/L2 fragment loads.
// Evidence: v0-v7 invariant at ~56us under pipeline/P-reg/occupancy changes;
// per-wave VALUBusy ~14%/wave constant -> waves internally stalled 86%;
// K/V per head-batch = 12.6 MB, fully L2-resident -> LDS staging is pure
// overhead (guide Common-mistake #7 / m169: dropping staging = +26%).
// Changes: no barriers, no ds ops, LDS=0; waves free-run.
//   K frag: kf = K[n][d] 16B/lane contiguous (exact MFMA A layout).
//   V frag: P sits in sigma-slot order; direct loads fetch V^T[d] at key
//   offsets {4q..+3, 16+4q..+3} / {32+4q, 48+4q} (= the v4-verified LDS
//   chunk contents, chunk quad / 4+quad) as 2x8B per fragment.
// Split-K x2 + combine kept verbatim from v7 (verified passing).
// ---------------------------------------------------------------------------
__global__ __launch_bounds__(256)
void attn_mfma(const unsigned short* __restrict__ Q, const unsigned short* __restrict__ K,
               const unsigned short* __restrict__ Vt_g,
               float* __restrict__ Opart, float* __restrict__ Lpart)
{
    const int tid = threadIdx.x;
    const int l = tid & 63;
    const int w = tid >> 6;
    const int quad = l >> 4;
    const int lc = l & 15;

    const int id = blockIdx.x;
    const int sp = blockIdx.y;           // key-split index
    const int bh = id % 24;              // b*HH + h
    const int bq = id / 24;              // q-tile
    const size_t hb = (size_t)bh * NN * DD;

    const f32x4 zero4 = {0.f, 0.f, 0.f, 0.f};

    // Q B-frags (pre-scaled by QSCALE): B[n=q=lc][k=d=quad*8+j]
    const int qrow = bq*64 + w*16 + lc;
    const bf16x8 qf0 = *(const bf16x8*)(Q + hb + (size_t)qrow*DD +      quad*8);
    const bf16x8 qf1 = *(const bf16x8*)(Q + hb + (size_t)qrow*DD + 32 + quad*8);

    f32x4 o[4];
    #pragma unroll
    for (int dj = 0; dj < 4; ++dj) o[dj] = zero4;
    float lsum = 0.f;

    // split-local base pointers
    const unsigned short* Kb = K + hb + (size_t)sp*KEYS_PER_SPLIT*DD;  // [n][d]
    const unsigned short* Vb = Vt_g + hb + sp*KEYS_PER_SPLIT;          // [d][n]

    for (int kt = 0; kt < KEYS_PER_SPLIT/64; ++kt) {   // 16 x 64-key groups
        const int k64 = kt*64;

        // ---- K fragment loads (8 x 16B, L1/L2-served) ----
        bf16x8 kf0[4], kf1[4];
        #pragma unroll
        for (int jf = 0; jf < 4; ++jf) {
            const unsigned short* kp = Kb + (size_t)(k64 + 16*jf + lc)*DD + quad*8;
            kf0[jf] = *(const bf16x8*)kp;
            kf1[jf] = *(const bf16x8*)(kp + 32);
        }

        // ---- S^T = K Q^T ----
        f32x4 st[4];
        #pragma unroll
        for (int jf = 0; jf < 4; ++jf) {
            f32x4 acc0 = MFMA(kf0[jf], qf0, zero4);
            st[jf] = MFMA(kf1[jf], qf1, acc0);
        }

        // ---- P = exp2(S^T) in registers (sigma-slot packing) ----
        f32x4 ev[4];
        #pragma unroll
        for (int jf = 0; jf < 4; ++jf) {
            ev[jf][0] = __builtin_amdgcn_exp2f(st[jf][0]);
            ev[jf][1] = __builtin_amdgcn_exp2f(st[jf][1]);
            ev[jf][2] = __builtin_amdgcn_exp2f(st[jf][2]);
            ev[jf][3] = __builtin_amdgcn_exp2f(st[jf][3]);
            lsum += (ev[jf][0] + ev[jf][1]) + (ev[jf][2] + ev[jf][3]);
        }
        u16x8 p0, p1;
        #pragma unroll
        for (int r = 0; r < 4; ++r) {
            p0[r]     = f2bf(ev[0][r]);
            p0[r + 4] = f2bf(ev[1][r]);
            p1[r]     = f2bf(ev[2][r]);
            p1[r + 4] = f2bf(ev[3][r]);
        }
        const bf16x8 pf0 = as_bf16x8(p0);
        const bf16x8 pf1 = as_bf16x8(p1);

        // ---- O^T += V^T P^T: V frags direct from global in sigma order ----
        #pragma unroll
        for (int dj = 0; dj < 4; ++dj) {
            const unsigned short* vrow = Vb + (size_t)(16*dj + lc)*NN + k64 + 4*quad;
            u16x4 a0 = *(const u16x4*)vrow;          // keys 4q..4q+3
            u16x4 a1 = *(const u16x4*)(vrow + 16);   // keys 16+4q..+3
            u16x4 a2 = *(const u16x4*)(vrow + 32);   // keys 32+4q..+3
            u16x4 a3 = *(const u16x4*)(vrow + 48);   // keys 48+4q..+3
            o[dj] = MFMA(combine48(a0, a1), pf0, o[dj]);
            o[dj] = MFMA(combine48(a2, a3), pf1, o[dj]);
        }
    }

    // partial denominator: reduce across the 4 quads (same q = lc)
    lsum += __shfl_xor(lsum, 16);
    lsum += __shfl_xor(lsum, 32);

    // partial O store (f32, no normalization): row = d = 16*dj + quad*4 + r,
    // col = q = lc. Layout Opart[sp][bh][n][d].
    const int n = bq*64 + w*16 + lc;
    float* op = Opart + ((size_t)(sp*24 + bh)*NN + n)*DD + quad*4;
    #pragma unroll
    for (int dj = 0; dj < 4; ++dj)
        *(f32x4*)(op + 16*dj) = o[dj];
    if (quad == 0)
        Lpart[(size_t)(sp*24 + bh)*NN + n] = lsum;
}

// ---------------------------------------------------------------------------
// Split-K combine: ctx[b,n,h*64+d] = (O0+O1)/(l0+l1), bf16. Deterministic
// fixed-order sum. 786432 threads = 3072 blocks.
// ---------------------------------------------------------------------------
#define RTOT (24*NN)    // 49152 rows (bh*NN + n)
__global__ __launch_bounds__(256)
void combine(const float* __restrict__ Op, const float* __restrict__ Lp,
             unsigned short* __restrict__ ctx)
{
    const int t = blockIdx.x * 256 + threadIdx.x;
    const int r = t >> 4;                // bh*2048 + n
    const int c = t & 15;                // d-quad (4 d's)
    const float4 a = *(const float4*)&Op[(size_t)r*DD + c*4];
    const float4 bv = *(const float4*)&Op[((size_t)RTOT + r)*DD + c*4];
    const float inv = 1.f / (Lp[r] + Lp[RTOT + r]);
    const int bh = r >> 11;
    const int n = r & (NN - 1);
    const int b = bh / 12;
    const int h = bh - b*12;
    ushort4 pk;
    pk.x = f2bf((a.x + bv.x) * inv);
    pk.y = f2bf((a.y + bv.y) * inv);
    pk.z = f2bf((a.z + bv.z) * inv);
    pk.w = f2bf((a.w + bv.w) * inv);
    *(ushort4*)&ctx[((size_t)(b*NN + n))*EE + h*DD + c*4] = pk;
}

// ---------------------------------------------------------------------------
extern "C" void kernel_launch(void* const* d_in, const int* in_sizes, int n_in,
                              void* d_out, int out_size, void* d_ws, size_t ws_size,
                              hipStream_t stream)
{
    const float* x     = (const float*)d_in[0];
    const float* w_qkv = (const float*)d_in[1];
    const float* b_qkv = (const float*)d_in[2];
    const float* w_o   = (const float*)d_in[3];
    const float* b_o   = (const float*)d_in[4];
    float* out = (float*)d_out;

    unsigned short* wsu = (unsigned short*)d_ws;
    const size_t XB = (size_t)MM * EE;
    const size_t WQ = (size_t)E3 * EE;
    const size_t WO = (size_t)EE * EE;
    const size_t HS = (size_t)BB * HH * NN * DD;
    unsigned short* xb   = wsu;
    unsigned short* wqb  = xb  + XB;
    unsigned short* wob  = wqb + WQ;
    unsigned short* qb   = wob + WO;      // [B][H][N][D] (scaled)
    unsigned short* kb   = qb  + HS;      // [B][H][N][D]
    unsigned short* vtb  = kb  + HS;      // [B][H][D][N]
    unsigned short* ctxb = vtb + HS;
    float* opart = (float*)(ctxb + HS);   // [NSPLIT][24][NN][DD] f32 (25.2 MB)
    float* lpart = opart + (size_t)NSPLIT * 24 * NN * DD;  // [NSPLIT][24][NN]

    cast3<<<(XB4 + WQ4 + WO4)/256, 256, 0, stream>>>(x, w_qkv, w_o, xb);

    dim3 g1(MM/128, E3/64);    // 32 x 36 = 1152 blocks
    gemm_qkv<<<g1, 256, 0, stream>>>(xb, wqb, b_qkv, qb, kb, vtb);

    dim3 g2(768, NSPLIT);      // 1536 blocks, LDS=0, VGPR-capped occupancy
    attn_mfma<<<g2, 256, 0, stream>>>(qb, kb, vtb, opart, lpart);

    combine<<<(RTOT*16)/256, 256, 0, stream>>>(opart, lpart, ctxb);

    dim3 g3(MM/64, EE/64);     // 64 x 12 = 768 blocks
    gemm_out<<<g3, 256, 0, stream>>>(ctxb, wob, b_o, out);
}